// Round 1
// baseline (1220.364 us; speedup 1.0000x reference)
//
#include <hip/hip_runtime.h>
#include <hip/hip_fp16.h>

#define N_TOK 4096
#define DIM   1024
#define HID   4096
#define NE    8

typedef __attribute__((ext_vector_type(8))) _Float16 f16x8;
typedef __attribute__((ext_vector_type(4))) float    f32x4;

__device__ __forceinline__ ushort f2h(float f) {
  union { _Float16 h; ushort u; } c;
  c.h = (_Float16)f;
  return c.u;
}

__global__ void init_meta(int* meta) {
  if (threadIdx.x < 8) meta[threadIdx.x] = 0;
}

// one wave per token: logits = x[n] @ gate_w + gate_b ; top1 = argmax (first max)
__global__ void gate_kernel(const float* __restrict__ x,
                            const float* __restrict__ gw,
                            const float* __restrict__ gb,
                            int* __restrict__ top1,
                            int* __restrict__ counts) {
  const int n = blockIdx.x;
  const int lane = threadIdx.x;
  const float* xr = x + (size_t)n * DIM;
  float acc[NE];
#pragma unroll
  for (int e = 0; e < NE; e++) acc[e] = 0.f;
  for (int i = lane; i < DIM; i += 64) {
    float xi = xr[i];
    float4 g0 = *(const float4*)(gw + (size_t)i * NE);
    float4 g1 = *(const float4*)(gw + (size_t)i * NE + 4);
    acc[0] += xi * g0.x; acc[1] += xi * g0.y;
    acc[2] += xi * g0.z; acc[3] += xi * g0.w;
    acc[4] += xi * g1.x; acc[5] += xi * g1.y;
    acc[6] += xi * g1.z; acc[7] += xi * g1.w;
  }
#pragma unroll
  for (int e = 0; e < NE; e++) {
#pragma unroll
    for (int off = 32; off > 0; off >>= 1)
      acc[e] += __shfl_down(acc[e], off);
  }
  if (lane == 0) {
    float best = acc[0] + gb[0]; int bi = 0;
#pragma unroll
    for (int e = 1; e < NE; e++) {
      float v = acc[e] + gb[e];
      if (v > best) { best = v; bi = e; }
    }
    top1[n] = bi;
    atomicAdd(&counts[bi], 1);
  }
}

__global__ void scan_kernel(int* meta) {
  if (threadIdx.x == 0 && blockIdx.x == 0) {
    int s = 0;
    for (int e = 0; e < NE; e++) {
      meta[8 + e]  = s;   // offsets
      meta[16 + e] = s;   // cursors
      s += meta[e];
    }
  }
}

__global__ void scatter_kernel(const int* __restrict__ top1,
                               int* __restrict__ cursors,
                               int* __restrict__ ids) {
  int n = blockIdx.x * 256 + threadIdx.x;
  if (n < N_TOK) {
    int e = top1[n];
    int p = atomicAdd(&cursors[e], 1);
    ids[p] = n;
  }
}

// GEMM1: h[p][0:4096] = relu(x[ids[p]] @ W1[e] + b1[e]), fp16 out, 128x128xBK64 tile
__global__ __launch_bounds__(256, 2) void gemm1(
    const float* __restrict__ x, const float* __restrict__ W1,
    const float* __restrict__ b1, const int* __restrict__ meta,
    const int* __restrict__ ids, ushort* __restrict__ h) {
  const int mb = blockIdx.x, nb = blockIdx.y, e = blockIdx.z;
  const int cnt = meta[e];
  if (mb * 128 >= cnt) return;
  const int off = meta[8 + e];
  const int tid = threadIdx.x;

  __shared__ __attribute__((aligned(16))) ushort Ab[2][128 * 72];
  __shared__ __attribute__((aligned(16))) ushort Bb[2][128 * 72];

  // A staging: thread = (kc: float4 chunk 0..15, rg: rowgroup 0..15), 8 rows each
  const int kc = tid & 15;
  const int rg = tid >> 4;
  const float* arow[8];
#pragma unroll
  for (int i = 0; i < 8; i++) {
    int p = off + mb * 128 + rg * 8 + i;
    const int pmax = off + cnt - 1;
    if (p > pmax) p = pmax;
    arow[i] = x + (size_t)ids[p] * DIM + kc * 4;
  }
  // B staging: thread = (hq: 4-col group 0..31, kg: 8-k group 0..7); transpose to [col][k]
  const int hq = tid & 31;
  const int kg = tid >> 5;
  const float* bbase = W1 + ((size_t)e * DIM + kg * 8) * HID + nb * 128 + hq * 4;

  float4 av[8]; float4 bv[8];

  auto load_tiles = [&](int kt) {
#pragma unroll
    for (int i = 0; i < 8; i++) av[i] = *(const float4*)(arow[i] + kt);
#pragma unroll
    for (int i = 0; i < 8; i++) bv[i] = *(const float4*)(bbase + (size_t)(kt + i) * HID);
  };

  auto write_tiles = [&](int b) {
#pragma unroll
    for (int i = 0; i < 8; i++) {
      const float* f = (const float*)&av[i];
      ushort4 wv;
      wv.x = f2h(f[0]); wv.y = f2h(f[1]); wv.z = f2h(f[2]); wv.w = f2h(f[3]);
      *(ushort4*)&Ab[b][(rg * 8 + i) * 72 + kc * 4] = wv;
    }
#pragma unroll
    for (int j = 0; j < 4; j++) {
      uint uu[4];
#pragma unroll
      for (int i = 0; i < 4; i++) {
        ushort lo = f2h(((const float*)&bv[2 * i])[j]);
        ushort hi = f2h(((const float*)&bv[2 * i + 1])[j]);
        uu[i] = (uint)lo | ((uint)hi << 16);
      }
      uint4 wv; wv.x = uu[0]; wv.y = uu[1]; wv.z = uu[2]; wv.w = uu[3];
      *(uint4*)&Bb[b][(hq * 4 + j) * 72 + kg * 8] = wv;
    }
  };

  const int wid = tid >> 6, lane = tid & 63;
  const int wr = wid >> 1, wc = wid & 1;
  const int fr = lane & 15, fq = lane >> 4;

  f32x4 acc[4][4] = {};

  auto compute = [&](int b) {
#pragma unroll
    for (int kk = 0; kk < 2; kk++) {
      f16x8 af[4], bf[4];
#pragma unroll
      for (int mi = 0; mi < 4; mi++)
        af[mi] = *(const f16x8*)&Ab[b][(wr * 64 + mi * 16 + fr) * 72 + kk * 32 + fq * 8];
#pragma unroll
      for (int ni = 0; ni < 4; ni++)
        bf[ni] = *(const f16x8*)&Bb[b][(wc * 64 + ni * 16 + fr) * 72 + kk * 32 + fq * 8];
#pragma unroll
      for (int mi = 0; mi < 4; mi++)
#pragma unroll
        for (int ni = 0; ni < 4; ni++)
          acc[mi][ni] = __builtin_amdgcn_mfma_f32_16x16x32_f16(af[mi], bf[ni], acc[mi][ni], 0, 0, 0);
    }
  };

  load_tiles(0);
  write_tiles(0);
  __syncthreads();
#pragma unroll 1
  for (int t = 0; t < 16; t += 2) {
    load_tiles((t + 1) * 64);
    compute(0);
    write_tiles(1);
    __syncthreads();
    if (t + 2 < 16) load_tiles((t + 2) * 64);
    compute(1);
    if (t + 2 < 16) write_tiles(0);
    __syncthreads();
  }

#pragma unroll
  for (int ni = 0; ni < 4; ni++) {
    int col = nb * 128 + wc * 64 + ni * 16 + fr;
    float bias = b1[(size_t)e * HID + col];
#pragma unroll
    for (int mi = 0; mi < 4; mi++) {
      int pr = mb * 128 + wr * 64 + mi * 16 + fq * 4;
#pragma unroll
      for (int q = 0; q < 4; q++) {
        int p = pr + q;
        if (p < cnt)
          h[(size_t)(off + p) * HID + col] = f2h(fmaxf(acc[mi][ni][q] + bias, 0.f));
      }
    }
  }
}

// GEMM2: out[ids[p]] = h[p] @ W2[e] + b2[e], 64x128xBK64 tile
__global__ __launch_bounds__(256, 2) void gemm2(
    const ushort* __restrict__ h, const float* __restrict__ W2,
    const float* __restrict__ b2, const int* __restrict__ meta,
    const int* __restrict__ ids, float* __restrict__ out) {
  const int mb = blockIdx.x, nb = blockIdx.y, e = blockIdx.z;
  const int cnt = meta[e];
  if (mb * 64 >= cnt) return;
  const int off = meta[8 + e];
  const int tid = threadIdx.x;

  __shared__ __attribute__((aligned(16))) ushort Ab[2][64 * 72];
  __shared__ __attribute__((aligned(16))) ushort Bb[2][128 * 72];

  const int kc = tid & 7;    // 8-half chunk within 64
  const int rg = tid >> 3;   // 0..31, 2 rows each
  const ushort* arow[2];
#pragma unroll
  for (int i = 0; i < 2; i++) {
    int p = off + mb * 64 + rg * 2 + i;
    const int pmax = off + cnt - 1;
    if (p > pmax) p = pmax;
    arow[i] = h + (size_t)p * HID + kc * 8;
  }
  const int hq = tid & 31;
  const int kg = tid >> 5;
  const float* bbase = W2 + ((size_t)e * HID + kg * 8) * DIM + nb * 128 + hq * 4;

  uint4 av[2]; float4 bv[8];

  auto load_tiles = [&](int kt) {
#pragma unroll
    for (int i = 0; i < 2; i++) av[i] = *(const uint4*)(arow[i] + kt);
#pragma unroll
    for (int i = 0; i < 8; i++) bv[i] = *(const float4*)(bbase + (size_t)(kt + i) * DIM);
  };

  auto write_tiles = [&](int b) {
#pragma unroll
    for (int i = 0; i < 2; i++)
      *(uint4*)&Ab[b][(rg * 2 + i) * 72 + kc * 8] = av[i];
#pragma unroll
    for (int j = 0; j < 4; j++) {
      uint uu[4];
#pragma unroll
      for (int i = 0; i < 4; i++) {
        ushort lo = f2h(((const float*)&bv[2 * i])[j]);
        ushort hi = f2h(((const float*)&bv[2 * i + 1])[j]);
        uu[i] = (uint)lo | ((uint)hi << 16);
      }
      uint4 wv; wv.x = uu[0]; wv.y = uu[1]; wv.z = uu[2]; wv.w = uu[3];
      *(uint4*)&Bb[b][(hq * 4 + j) * 72 + kg * 8] = wv;
    }
  };

  const int wid = tid >> 6, lane = tid & 63;
  const int wr = wid >> 1, wc = wid & 1;
  const int fr = lane & 15, fq = lane >> 4;

  f32x4 acc[2][4] = {};

  auto compute = [&](int b) {
#pragma unroll
    for (int kk = 0; kk < 2; kk++) {
      f16x8 af[2], bf[4];
#pragma unroll
      for (int mi = 0; mi < 2; mi++)
        af[mi] = *(const f16x8*)&Ab[b][(wr * 32 + mi * 16 + fr) * 72 + kk * 32 + fq * 8];
#pragma unroll
      for (int ni = 0; ni < 4; ni++)
        bf[ni] = *(const f16x8*)&Bb[b][(wc * 64 + ni * 16 + fr) * 72 + kk * 32 + fq * 8];
#pragma unroll
      for (int mi = 0; mi < 2; mi++)
#pragma unroll
        for (int ni = 0; ni < 4; ni++)
          acc[mi][ni] = __builtin_amdgcn_mfma_f32_16x16x32_f16(af[mi], bf[ni], acc[mi][ni], 0, 0, 0);
    }
  };

  load_tiles(0);
  write_tiles(0);
  __syncthreads();
#pragma unroll 1
  for (int t = 0; t < 64; t += 2) {
    load_tiles((t + 1) * 64);
    compute(0);
    write_tiles(1);
    __syncthreads();
    if (t + 2 < 64) load_tiles((t + 2) * 64);
    compute(1);
    if (t + 2 < 64) write_tiles(0);
    __syncthreads();
  }

  int tok[2][4];
#pragma unroll
  for (int mi = 0; mi < 2; mi++)
#pragma unroll
    for (int q = 0; q < 4; q++) {
      int p = mb * 64 + wr * 32 + mi * 16 + fq * 4 + q;
      tok[mi][q] = (p < cnt) ? ids[off + p] : -1;
    }
#pragma unroll
  for (int ni = 0; ni < 4; ni++) {
    int col = nb * 128 + wc * 64 + ni * 16 + fr;
    float bias = b2[(size_t)e * DIM + col];
#pragma unroll
    for (int mi = 0; mi < 2; mi++)
#pragma unroll
      for (int q = 0; q < 4; q++)
        if (tok[mi][q] >= 0)
          out[(size_t)tok[mi][q] * DIM + col] = acc[mi][ni][q] + bias;
  }
}

extern "C" void kernel_launch(void* const* d_in, const int* in_sizes, int n_in,
                              void* d_out, int out_size, void* d_ws, size_t ws_size,
                              hipStream_t stream) {
  const float* x  = (const float*)d_in[0];
  const float* gw = (const float*)d_in[1];
  const float* gb = (const float*)d_in[2];
  const float* W1 = (const float*)d_in[3];
  const float* b1 = (const float*)d_in[4];
  const float* W2 = (const float*)d_in[5];
  const float* b2 = (const float*)d_in[6];
  float* out = (float*)d_out;

  // ws layout: [0..7] counts, [8..15] offsets, [16..23] cursors,
  //            [24..] top1 (4096), then ids (4096); h (fp16, 32MB) at +64KB
  int* meta = (int*)d_ws;
  int* top1 = meta + 24;
  int* ids  = meta + 24 + N_TOK;
  ushort* h = (ushort*)((char*)d_ws + 65536);

  hipLaunchKernelGGL(init_meta, dim3(1), dim3(64), 0, stream, meta);
  hipLaunchKernelGGL(gate_kernel, dim3(N_TOK), dim3(64), 0, stream, x, gw, gb, top1, meta);
  hipLaunchKernelGGL(scan_kernel, dim3(1), dim3(64), 0, stream, meta);
  hipLaunchKernelGGL(scatter_kernel, dim3(N_TOK / 256), dim3(256), 0, stream, top1, meta + 16, ids);
  hipLaunchKernelGGL(gemm1, dim3(32, 32, 8), dim3(256), 0, stream, x, W1, b1, meta, ids, h);
  hipLaunchKernelGGL(gemm2, dim3(64, 8, 8), dim3(256), 0, stream, h, W2, b2, meta, ids, out);
}